// Round 2
// baseline (1039.438 us; speedup 1.0000x reference)
//
#include <hip/hip_runtime.h>
#include <hip/hip_bf16.h>

#define VOCAB 32000
#define EMB   64
#define HID   64
#define NB    16
#define NS    256
#define G3    192   // 3*HID

typedef __bf16 bf16x8  __attribute__((ext_vector_type(8)));
typedef short  short8  __attribute__((ext_vector_type(8)));
typedef float  floatx4 __attribute__((ext_vector_type(4)));

__device__ __forceinline__ float bf2f(__hip_bfloat16 v) { return __bfloat162float(v); }

// RNE fp32 -> bf16 bit pattern (no NaN inputs possible here)
__device__ __forceinline__ short f2bf_bits(float f) {
    unsigned int u = __float_as_uint(f);
    unsigned int r = (u + 0x7FFFu + ((u >> 16) & 1u)) >> 16;
    return (short)r;
}

// Runtime dtype detection: true if the array at p holds bf16 data, false if fp32.
// Looks at first 64 dwords. bf16 data: low half of each dword is a bf16 with sane
// exponent (~99% in [115,130] for N(0,~0.125) weights). fp32 data: those bits are
// uniform mantissa bits (~6% hit rate). Ballot over one wave separates by >10 sigma.
__device__ __forceinline__ bool detect_bf16(const void* p) {
    const unsigned int* w = (const unsigned int*)p;
    unsigned int word = w[threadIdx.x & 63];
    unsigned int e = (word >> 7) & 0xFFu;
    int pred = (e >= 115u) && (e <= 130u);
    unsigned long long m = __ballot(pred);
    return __popcll(m) > 32;
}

// lane-broadcast of a float via v_readlane
__device__ __forceinline__ float bcastf(float v, int l) {
    return __uint_as_float(__builtin_amdgcn_readlane(__float_as_uint(v), l));
}

// ---------------------------------------------------------------------------
// K1: xp[m][g] = sum_e emb[tok[m]][e] * w_ih[g][e] + b_ih[g]   (m = b*NS + s)
// xp lives in d_out (dead scratch until K3 overwrites all of d_out).
// ---------------------------------------------------------------------------
__global__ __launch_bounds__(G3) void k_embed_proj(
    const int* __restrict__ tokens,
    const void* __restrict__ emb_raw,
    const void* __restrict__ w_ih_raw,
    const void* __restrict__ b_ih_raw,
    float* __restrict__ xp)
{
    const bool isbf = detect_bf16(w_ih_raw);
    __shared__ float e_s[EMB];
    const int m   = blockIdx.x;
    const int tid = threadIdx.x;
    const int tok = tokens[m];
    if (tid < EMB) {
        e_s[tid] = isbf ? bf2f(((const __hip_bfloat16*)emb_raw)[tok * EMB + tid])
                        : ((const float*)emb_raw)[tok * EMB + tid];
    }
    __syncthreads();

    float acc = isbf ? bf2f(((const __hip_bfloat16*)b_ih_raw)[tid])
                     : ((const float*)b_ih_raw)[tid];
    if (isbf) {
        const __hip_bfloat16* wrow = (const __hip_bfloat16*)w_ih_raw + tid * EMB;
#pragma unroll
        for (int k0 = 0; k0 < EMB; k0 += 8) {
            bf16x8 wv = *reinterpret_cast<const bf16x8*>(wrow + k0);
#pragma unroll
            for (int j = 0; j < 8; ++j) acc += e_s[k0 + j] * (float)wv[j];
        }
    } else {
        const float* wrow = (const float*)w_ih_raw + tid * EMB;
#pragma unroll
        for (int k0 = 0; k0 < EMB; k0 += 4) {
            floatx4 wv = *reinterpret_cast<const floatx4*>(wrow + k0);
#pragma unroll
            for (int j = 0; j < 4; ++j) acc += e_s[k0 + j] * wv[j];
        }
    }
    xp[m * G3 + tid] = acc;
}

// ---------------------------------------------------------------------------
// K2: sequential GRU scan. One block per batch element, 192 threads (3 waves).
// Thread g owns w_hh row g in 64 VGPRs (fp32); h broadcast via v_readlane.
// All arithmetic fp32; hs written as bf16 for the MFMA logits stage.
// ---------------------------------------------------------------------------
__global__ __launch_bounds__(G3) void k_gru_scan(
    const float* __restrict__ xp,
    const void* __restrict__ w_hh_raw,
    const void* __restrict__ b_hh_raw,
    __hip_bfloat16* __restrict__ hs)
{
    const bool isbf = detect_bf16(w_hh_raw);
    __shared__ float h_s[HID];
    __shared__ float hp_s[G3];
    const int b    = blockIdx.x;
    const int g    = threadIdx.x;
    const int lane = g & 63;

    float wreg[HID];
    if (isbf) {
        const __hip_bfloat16* wrow = (const __hip_bfloat16*)w_hh_raw + g * HID;
#pragma unroll
        for (int k0 = 0; k0 < HID; k0 += 8) {
            bf16x8 wv = *reinterpret_cast<const bf16x8*>(wrow + k0);
#pragma unroll
            for (int j = 0; j < 8; ++j) wreg[k0 + j] = (float)wv[j];
        }
    } else {
        const float* wrow = (const float*)w_hh_raw + g * HID;
#pragma unroll
        for (int k0 = 0; k0 < HID; k0 += 4) {
            floatx4 wv = *reinterpret_cast<const floatx4*>(wrow + k0);
#pragma unroll
            for (int j = 0; j < 4; ++j) wreg[k0 + j] = wv[j];
        }
    }
    const float bh = isbf ? bf2f(((const __hip_bfloat16*)b_hh_raw)[g])
                          : ((const float*)b_hh_raw)[g];

    if (g < HID) h_s[g] = 0.f;
    __syncthreads();

    const float* xpb = xp + b * NS * G3;
    for (int s = 0; s < NS; ++s) {
        float xr = 0.f, xz = 0.f, xn = 0.f;
        if (g < HID) {
            const float* xrow = xpb + s * G3;
            xr = xrow[g];
            xz = xrow[HID + g];
            xn = xrow[2 * HID + g];
        }

        float hval = h_s[lane];   // lane k holds h[k] (identical in every wave)
        float a0 = 0.f, a1 = 0.f, a2 = 0.f, a3 = 0.f;
#pragma unroll
        for (int k = 0; k < HID; k += 4) {
            a0 += bcastf(hval, k    ) * wreg[k    ];
            a1 += bcastf(hval, k + 1) * wreg[k + 1];
            a2 += bcastf(hval, k + 2) * wreg[k + 2];
            a3 += bcastf(hval, k + 3) * wreg[k + 3];
        }
        hp_s[g] = ((a0 + a1) + (a2 + a3)) + bh;
        __syncthreads();

        if (g < HID) {
            const float r = 1.f / (1.f + expf(-(xr + hp_s[g])));
            const float z = 1.f / (1.f + expf(-(xz + hp_s[HID + g])));
            const float n = tanhf(xn + r * hp_s[2 * HID + g]);
            const float hnew = (1.f - z) * n + z * h_s[g];
            h_s[g] = hnew;
            hs[(b * NS + s) * HID + g] = __float2bfloat16(hnew);
        }
        __syncthreads();
    }
}

// ---------------------------------------------------------------------------
// K3: out[m][v] = sum_k hs[m][k] * w_out[v][k] + b_out[v].
// mfma_f32_16x16x32_bf16; block = 4 waves, each wave does 16(M)x64(N) per t-tile.
// A layout: A[m=lane&15][k=quad*8+j]; B layout: B[k=quad*8+j][n=lane&15];
// C layout: col=lane&15, row=quad*4+reg (m89-verified).
// ---------------------------------------------------------------------------
__global__ __launch_bounds__(256) void k_logits(
    const __hip_bfloat16* __restrict__ hs,
    const void* __restrict__ w_out_raw,
    const void* __restrict__ b_out_raw,
    void* __restrict__ out_raw)
{
    const bool isbf = detect_bf16(w_out_raw);
    const int mtile = blockIdx.y;            // 0..255 (16 rows each)
    const int ncb   = blockIdx.x;            // 0..124 (256 cols each)
    const int wave  = threadIdx.x >> 6;      // 0..3
    const int lane  = threadIdx.x & 63;
    const int quad  = lane >> 4;
    const int l15   = lane & 15;

    const __hip_bfloat16* arow = hs + (mtile * 16 + l15) * HID;
    const bf16x8 a0 = *reinterpret_cast<const bf16x8*>(arow + quad * 8);
    const bf16x8 a1 = *reinterpret_cast<const bf16x8*>(arow + 32 + quad * 8);

    const int ncol_wave = ncb * 256 + wave * 64;
#pragma unroll
    for (int t = 0; t < 4; ++t) {
        const int ncol = ncol_wave + t * 16;
        bf16x8 b0, b1;
        if (isbf) {
            const __hip_bfloat16* brow = (const __hip_bfloat16*)w_out_raw + (ncol + l15) * HID;
            b0 = *reinterpret_cast<const bf16x8*>(brow + quad * 8);
            b1 = *reinterpret_cast<const bf16x8*>(brow + 32 + quad * 8);
        } else {
            const float* browf = (const float*)w_out_raw + (ncol + l15) * HID;
            floatx4 f0 = *reinterpret_cast<const floatx4*>(browf + quad * 8);
            floatx4 f1 = *reinterpret_cast<const floatx4*>(browf + quad * 8 + 4);
            floatx4 f2 = *reinterpret_cast<const floatx4*>(browf + 32 + quad * 8);
            floatx4 f3 = *reinterpret_cast<const floatx4*>(browf + 32 + quad * 8 + 4);
            short8 s0, s1;
#pragma unroll
            for (int j = 0; j < 4; ++j) {
                s0[j] = f2bf_bits(f0[j]); s0[4 + j] = f2bf_bits(f1[j]);
                s1[j] = f2bf_bits(f2[j]); s1[4 + j] = f2bf_bits(f3[j]);
            }
            b0 = __builtin_bit_cast(bf16x8, s0);
            b1 = __builtin_bit_cast(bf16x8, s1);
        }

        floatx4 acc = {0.f, 0.f, 0.f, 0.f};
        acc = __builtin_amdgcn_mfma_f32_16x16x32_bf16(a0, b0, acc, 0, 0, 0);
        acc = __builtin_amdgcn_mfma_f32_16x16x32_bf16(a1, b1, acc, 0, 0, 0);

        const float bias = isbf ? bf2f(((const __hip_bfloat16*)b_out_raw)[ncol + l15])
                                : ((const float*)b_out_raw)[ncol + l15];
        if (isbf) {
            __hip_bfloat16* outb = (__hip_bfloat16*)out_raw;
#pragma unroll
            for (int i = 0; i < 4; ++i) {
                const int row = mtile * 16 + quad * 4 + i;
                outb[(size_t)row * VOCAB + ncol + l15] = __float2bfloat16(acc[i] + bias);
            }
        } else {
            float* outf = (float*)out_raw;
#pragma unroll
            for (int i = 0; i < 4; ++i) {
                const int row = mtile * 16 + quad * 4 + i;
                outf[(size_t)row * VOCAB + ncol + l15] = acc[i] + bias;
            }
        }
    }
}

// ---------------------------------------------------------------------------
extern "C" void kernel_launch(void* const* d_in, const int* in_sizes, int n_in,
                              void* d_out, int out_size, void* d_ws, size_t ws_size,
                              hipStream_t stream)
{
    const int*  tokens = (const int*)d_in[0];
    const void* emb    = d_in[1];
    const void* w_ih   = d_in[2];
    const void* w_hh   = d_in[3];
    const void* b_ih   = d_in[4];
    const void* b_hh   = d_in[5];
    const void* w_out  = d_in[6];
    const void* b_out  = d_in[7];

    // xp scratch lives in d_out's first 3 MiB (dead until k_logits overwrites
    // the whole output); hs (512 KiB) is the only d_ws use.
    float* xp = (float*)d_out;
    __hip_bfloat16* hs = (__hip_bfloat16*)d_ws;

    k_embed_proj<<<NB * NS, G3, 0, stream>>>(tokens, emb, w_ih, b_ih, xp);
    k_gru_scan<<<NB, G3, 0, stream>>>(xp, w_hh, b_hh, hs);
    dim3 grid3(VOCAB / 256, (NB * NS) / 16);
    k_logits<<<grid3, 256, 0, stream>>>(hs, w_out, b_out, d_out);
}